// Round 9
// baseline (1377.003 us; speedup 1.0000x reference)
//
#include <hip/hip_runtime.h>
#include <hip/hip_bf16.h>
#include <cstdint>

// ---------------------------------------------------------------------------
// KAN 2-layer forward, FUSED: expansion folded into the GEMM A-staging.
// Round-9 (vs r8 pass @984us):
//  * expand_aug DELETED. gemm_fused stages raw x (fp32) into LDS via GLD16,
//    expands basis/silu once per i-block into fp32 register state (double-
//    buffered across ib boundary), and ds_writes each 32-k c-subtile into
//    the proven swizzled A-layout. Saves 432MB HBM write + 432MB read + 2
//    dispatches; expansion VALU (~4000cy/SIMD/i-block) hides under MFMA
//    (4640cy/i-block, separate pipes per m114).
//  * Geometry: BM=128 x BN=256, 8 waves (2M x 4N), per-wave 64x64, acc=64
//    regs -> state (96) + acc fits <=256 (2 waves/SIMD preserved).
//  * W layout (kperm i-block-major, r8) and B staging path unchanged.
//  * prep_w vectorized: 4 i/thread, contiguous 128B coef reads, 8B stores.
// Sync chain (hand-verified): A-writes -> lgkmcnt(0) -> barrier -> (next
// tile's barrier) -> reads. X staged c==4, retired by c==5 counted vmcnt +
// barriers, read c==7. B depth-2, vmcnt(4) steady (never 0), peeled tails.
// ws: h1 fp32 [0,64MiB) | W bf16 [64,100MiB). No Aug.
// ---------------------------------------------------------------------------

typedef __attribute__((ext_vector_type(8))) short short8;
typedef __attribute__((ext_vector_type(4))) short short4v;
typedef __attribute__((ext_vector_type(4))) float f32x4;

#define GLD16(gp, lp)                                                          \
  __builtin_amdgcn_global_load_lds(                                           \
      (const __attribute__((address_space(1))) unsigned int*)(gp),             \
      (__attribute__((address_space(3))) unsigned int*)(lp), 16, 0, 0)

__device__ __forceinline__ unsigned short f2bf(float f) {
  __hip_bfloat16 h = __float2bfloat16(f);
  return *reinterpret_cast<unsigned short*>(&h);
}
__device__ __forceinline__ unsigned int pkbf(float a, float b) {
  unsigned int r;
  asm("v_cvt_pk_bf16_f32 %0, %1, %2" : "=v"(r) : "v"(a), "v"(b));
  return r;
}

// ---- pack weights: W[o, kperm(c,i)], bf16; kperm = (i/32)*288+c*32+(i%32) --
__global__ void prep_w(const float* __restrict__ coef, const float* __restrict__ sb,
                       const float* __restrict__ sp, const float* __restrict__ mask,
                       __hip_bfloat16* __restrict__ W, int O, int I) {
  long idx = (long)blockIdx.x * blockDim.x + threadIdx.x;
  long total = (long)O * (I >> 2);
  if (idx >= total) return;
  int qtr = I >> 2;
  int iq = (int)(idx % qtr);
  int o  = (int)(idx / qtr);
  int i  = iq << 2;
  size_t oi = (size_t)o * I + i;
  float4 mk4 = *(const float4*)(mask + oi);
  float4 sp4 = *(const float4*)(sp + oi);
  float4 sb4 = *(const float4*)(sb + oi);
  float spm[4] = {sp4.x * mk4.x, sp4.y * mk4.y, sp4.z * mk4.z, sp4.w * mk4.w};
  float cf[4][8];
  const float4* cp = (const float4*)(coef + oi * 8);
#pragma unroll
  for (int e = 0; e < 4; e++) {
    float4 a = cp[e * 2], b = cp[e * 2 + 1];
    cf[e][0] = a.x; cf[e][1] = a.y; cf[e][2] = a.z; cf[e][3] = a.w;
    cf[e][4] = b.x; cf[e][5] = b.y; cf[e][6] = b.z; cf[e][7] = b.w;
  }
  __hip_bfloat16* base = W + (size_t)o * (size_t)(9 * I) + (i >> 5) * 288 + (i & 31);
#pragma unroll
  for (int c = 0; c < 8; c++) {
    short4v pk;
#pragma unroll
    for (int e = 0; e < 4; e++) pk[e] = (short)f2bf(cf[e][c] * spm[e]);
    *(short4v*)(base + c * 32) = pk;
  }
  short4v ps;
  ps[0] = (short)f2bf(sb4.x * mk4.x); ps[1] = (short)f2bf(sb4.y * mk4.y);
  ps[2] = (short)f2bf(sb4.z * mk4.z); ps[3] = (short)f2bf(sb4.w * mk4.w);
  *(short4v*)(base + 8 * 32) = ps;
}

// ---- fused GEMM: C[m,o] = sum_k aug(X)[m,k]*W[o,k] + bias[o], fp32 out ----
// BM=128 x BN=256, BK=32, 8 waves = 2M x 4N (per-wave 64x64), 3 LDS buffers
// (A 8KB + B 16KB each) + 16KB x-stage region. Swizzle (both sides):
// byte ^= ((row>>1)&3)<<4 (0 conflicts, r6-verified).
struct KState { float w[8][4]; float s[8]; int j[8]; };

__global__ __launch_bounds__(512, 2) void gemm_fused(
    const float* __restrict__ X, const __hip_bfloat16* __restrict__ Bw,
    const float* __restrict__ bias, float* __restrict__ Cout, int N, int I) {
  constexpr int BUFB = 8192 + 16384;       // A + B per buffer
  constexpr int XOFF = 3 * BUFB;           // x-stage region (16 KB)
  __shared__ __attribute__((aligned(16))) char lds[3 * BUFB + 16384];
  const int K = 9 * I, NB = I >> 5, NT = 9 * NB;

  const int t = threadIdx.x;
  const int w = t >> 6, l = t & 63;
  const int wr = w >> 2, wc = w & 3;
  const int lr = l & 15;
  const int kbs = ((l >> 4) * 16) ^ (((lr >> 1) & 3) << 4);

  unsigned nwg = gridDim.x * gridDim.y;
  unsigned lin = blockIdx.y * gridDim.x + blockIdx.x;
  unsigned swz = (lin & 7) * (nwg >> 3) + (lin >> 3);
  unsigned bx = swz % gridDim.x, by = swz / gridDim.x;
  size_t brow = (size_t)by * 128, bcol = (size_t)bx * 256;

  f32x4 acc[4][4];
#pragma unroll
  for (int m = 0; m < 4; m++)
#pragma unroll
    for (int n = 0; n < 4; n++) acc[m][n] = (f32x4){0.f, 0.f, 0.f, 0.f};

  // B staging (GLD16, pre-swizzled source), W rows bcol..bcol+255
  const int srow  = t >> 2;
  const int scolb = ((t & 3) * 16) ^ (((srow >> 1) & 3) << 4);
  const __hip_bfloat16* gB0 = Bw + (bcol + srow) * (size_t)K + (scolb >> 1);
  const __hip_bfloat16* gB1 = gB0 + (size_t)128 * K;
  // X staging (GLD16 linear): lds offset o=w*1024+lane*16 -> row o/128, col (o%128)/4
  const float* gX0 = X + (brow + (t >> 3)) * (size_t)I + (t & 7) * 4;
  const float* gX1 = gX0 + (size_t)64 * I;

  char* ldsp = (char*)lds;
  const int paOff = (wr * 64 + lr) * 64 + kbs;           // A: + m*1024 + q*BUFB
  const int pbOff = 8192 + (wc * 64 + lr) * 64 + kbs;    // B: + n*1024 + q*BUFB
  const int awOff = (t >> 2) * 64 + (((t & 3) * 16) ^ ((((t >> 2) >> 1) & 3) << 4));
  const int xrOff = XOFF + (t >> 2) * 128 + (t & 3) * 32;

  auto STAGE_B = [&](int kt, int q) {
    char* bp = ldsp + q * BUFB + 8192;
    GLD16(gB0 + (kt << 5), bp + w * 1024);
    GLD16(gB1 + (kt << 5), bp + 8192 + w * 1024);
  };
  auto STAGE_X = [&](int ib) {
    GLD16(gX0 + ib * 32, ldsp + XOFF + w * 1024);
    GLD16(gX1 + ib * 32, ldsp + XOFF + 8192 + w * 1024);
  };
  auto EXPAND = [&](KState& st) {
    float4 xa = *(const float4*)(ldsp + xrOff);
    float4 xb = *(const float4*)(ldsp + xrOff + 16);
    float xv[8] = {xa.x, xa.y, xa.z, xa.w, xb.x, xb.y, xb.z, xb.w};
#pragma unroll
    for (int e = 0; e < 8; e++) {
      float x = xv[e];
      st.s[e] = x / (1.0f + __expf(-x));
      float u  = (x + 2.2f) * 2.5f;
      float fj = floorf(u);
      int   jj = (int)fj;
      jj = jj < -1 ? -1 : (jj > 12 ? 12 : jj);
      st.j[e] = jj;
      float tt = u - fj, omt = 1.0f - tt;
      float t2 = tt * tt, t3 = t2 * tt;
      st.w[e][0] = omt * omt * omt * (1.0f / 6.0f);
      st.w[e][1] = (3.0f * t3 - 6.0f * t2 + 4.0f) * (1.0f / 6.0f);
      st.w[e][2] = (-3.0f * t3 + 3.0f * t2 + 3.0f * tt + 1.0f) * (1.0f / 6.0f);
      st.w[e][3] = t3 * (1.0f / 6.0f);
    }
  };
  auto WRITEA = [&](KState& st, int cw, int q) {
    float v[8];
    if (cw == 8) {
#pragma unroll
      for (int e = 0; e < 8; e++) v[e] = st.s[e];
    } else {
#pragma unroll
      for (int e = 0; e < 8; e++) {
        int d = st.j[e] - cw;
        float r = 0.f;
        r = (d == 3) ? st.w[e][0] : r;
        r = (d == 2) ? st.w[e][1] : r;
        r = (d == 1) ? st.w[e][2] : r;
        r = (d == 0) ? st.w[e][3] : r;
        v[e] = r;
      }
    }
    uint4 pk;
    pk.x = pkbf(v[0], v[1]); pk.y = pkbf(v[2], v[3]);
    pk.z = pkbf(v[4], v[5]); pk.w = pkbf(v[6], v[7]);
    *(uint4*)(ldsp + q * BUFB + awOff) = pk;
  };

  short8 aq[4], bq[4];
  auto COMPUTE = [&](int q) {
    const char* pa = ldsp + q * BUFB + paOff;
    const char* pb = ldsp + q * BUFB + pbOff;
#pragma unroll
    for (int n = 0; n < 4; n++) bq[n] = *(const short8*)(pb + n * 1024);
#pragma unroll
    for (int m = 0; m < 4; m++) aq[m] = *(const short8*)(pa + m * 1024);
    __builtin_amdgcn_s_setprio(1);
#pragma unroll
    for (int m = 0; m < 4; m++)
#pragma unroll
      for (int n = 0; n < 4; n++)
        acc[m][n] = __builtin_amdgcn_mfma_f32_16x16x32_bf16(aq[m], bq[n], acc[m][n], 0, 0, 0);
    __builtin_amdgcn_s_setprio(0);
  };

  KState s0, s1;

  // prologue: X(0), B(0), B(1); X retired by vmcnt(4); expand ib0; A(0)
  STAGE_X(0);
  STAGE_B(0, 0);
  STAGE_B(1, 1);
  asm volatile("s_waitcnt vmcnt(4)" ::: "memory");
  __builtin_amdgcn_s_barrier();
  EXPAND(s0);
  WRITEA(s0, 0, 0);

  int q0 = 0, c = 0, ib = 0;
  for (int kt = 0; kt < NT - 2; ++kt) {
    int q1 = q0 + 1; if (q1 == 3) q1 = 0;
    int q2 = q1 + 1; if (q2 == 3) q2 = 0;
    if (c == 4 && ib + 1 < NB) STAGE_X(ib + 1);
    STAGE_B(kt + 2, q2);
    int cw, pw;
    if (c == 8) { cw = 0; pw = (ib + 1) & 1; }
    else        { cw = c + 1; pw = ib & 1; }
    if (pw == 0) WRITEA(s0, cw, q1); else WRITEA(s1, cw, q1);
    if (c == 7 && ib + 1 < NB) {
      if (((ib + 1) & 1) == 0) EXPAND(s0); else EXPAND(s1);
    }
    asm volatile("s_waitcnt vmcnt(4) lgkmcnt(0)" ::: "memory");
    __builtin_amdgcn_s_barrier();
    COMPUTE(q0);
    __builtin_amdgcn_s_barrier();
    q0 = q1;
    if (++c == 9) { c = 0; ++ib; }
  }
  // peel kt = NT-2 (c == 7 here; writes A(NT-1) with cw=8)
  {
    int q1 = q0 + 1; if (q1 == 3) q1 = 0;
    if ((ib & 1) == 0) WRITEA(s0, 8, q1); else WRITEA(s1, 8, q1);
    asm volatile("s_waitcnt vmcnt(2) lgkmcnt(0)" ::: "memory");
    __builtin_amdgcn_s_barrier();
    COMPUTE(q0);
    __builtin_amdgcn_s_barrier();
    q0 = q1;
  }
  // peel kt = NT-1
  {
    asm volatile("s_waitcnt vmcnt(0) lgkmcnt(0)" ::: "memory");
    __builtin_amdgcn_s_barrier();
    COMPUTE(q0);
  }

  // epilogue
  const int orow = (l >> 4) << 2;
#pragma unroll
  for (int n = 0; n < 4; n++) {
    size_t col = bcol + (size_t)wc * 64 + n * 16 + lr;
    float bv = bias[col];
#pragma unroll
    for (int m = 0; m < 4; m++) {
      size_t row = brow + (size_t)wr * 64 + m * 16 + orow;
#pragma unroll
      for (int r = 0; r < 4; r++)
        Cout[(row + r) * (size_t)N + col] = acc[m][n][r] + bv;
    }
  }
}

// ---------------------------------------------------------------------------
extern "C" void kernel_launch(void* const* d_in, const int* in_sizes, int n_in,
                              void* d_out, int out_size, void* d_ws, size_t ws_size,
                              hipStream_t stream) {
  const float* x     = (const float*)d_in[0];
  const float* coef0 = (const float*)d_in[1];
  const float* sb0   = (const float*)d_in[2];
  const float* sp0   = (const float*)d_in[3];
  const float* mask0 = (const float*)d_in[4];
  const float* bias0 = (const float*)d_in[5];
  const float* coef1 = (const float*)d_in[6];
  const float* sb1   = (const float*)d_in[7];
  const float* sp1   = (const float*)d_in[8];
  const float* mask1 = (const float*)d_in[9];
  const float* bias1 = (const float*)d_in[10];
  float* out = (float*)d_out;

  const int B = 8192, D0 = 1024, D1 = 2048, D2 = 1024;

  char* ws = (char*)d_ws;
  float*          h1 = (float*)ws;                                  // 64 MiB
  __hip_bfloat16* W  = (__hip_bfloat16*)(ws + (size_t)67108864);    // 36 MiB

  // ---- layer 0 ----
  {
    long nt = (long)D1 * (D0 / 4);
    prep_w<<<(unsigned)((nt + 255) / 256), 256, 0, stream>>>(coef0, sb0, sp0, mask0, W, D1, D0);
    dim3 g0(D1 / 256, B / 128);  // (8, 64) = 512 blocks
    gemm_fused<<<g0, 512, 0, stream>>>(x, W, bias0, h1, D1, D0);
  }
  // ---- layer 1 ----
  {
    long nt = (long)D2 * (D1 / 4);
    prep_w<<<(unsigned)((nt + 255) / 256), 256, 0, stream>>>(coef1, sb1, sp1, mask1, W, D2, D1);
    dim3 g1(D2 / 256, B / 128);  // (4, 64) = 256 blocks
    gemm_fused<<<g1, 512, 0, stream>>>(h1, W, bias1, out, D2, D1);
  }
}

// Round 10
// 993.687 us; speedup vs baseline: 1.3858x; 1.3858x over previous
//
#include <hip/hip_runtime.h>
#include <hip/hip_bf16.h>
#include <cstdint>

// ---------------------------------------------------------------------------
// KAN 2-layer forward as two bf16 MFMA GEMMs (fp32 output).
// Round-10 (vs r8 pass @984us; r9 fusion regression reverted):
//  * GEMM rebuilt at BK=64 (was 32): 512 MFMA/CU between one barrier pair
//    (was 256) -> per-tile overhead (~1360cy, the real limiter: 48% duty at
//    BK=32) halves per MFMA. 2 LDS buffers x (A 32KB + B BN*128B) = 128KB
//    (BN=256). Schedule per tile t: COMPUTE (4 lgkm-gated phases, NO inner
//    barriers) -> barrier(reads done) -> STAGE L(t+2) into just-read buf ->
//    vmcnt(L) [2L outstanding, FIFO-drains exactly L(t+1)] -> barrier.
//    Counted waits only (tail peeled to vmcnt(0)); ~1-tile flight >> HBM lat.
//  * 128B-row swizzle: elem(row,kbyte) at slot ((kbyte>>4) ^ (row&7)), i.e.
//    read slot = ((l>>4)+kh*4)^(lr&7); k1 addr = k0 addr ^ 64 (bit-verified).
//    Residual 2-way conflict = free (m136). Pre-swizzled global source.
//  * L1 uses BN=128 (grid (8,32)=256 blocks, full GPU).
//  * expand_aug: 8 elems/thread, 9x 16B stores. prep_w: r9's vectorized.
// ws: h1 fp32 [0,64MiB) | W bf16 [64,100MiB) | Aug bf16 [100MiB,...)
// ---------------------------------------------------------------------------

typedef __attribute__((ext_vector_type(8))) short short8;
typedef __attribute__((ext_vector_type(4))) short short4v;
typedef __attribute__((ext_vector_type(4))) float f32x4;

#define GLD16(gp, lp)                                                          \
  __builtin_amdgcn_global_load_lds(                                           \
      (const __attribute__((address_space(1))) unsigned int*)(gp),             \
      (__attribute__((address_space(3))) unsigned int*)(lp), 16, 0, 0)

__device__ __forceinline__ unsigned short f2bf(float f) {
  __hip_bfloat16 h = __float2bfloat16(f);
  return *reinterpret_cast<unsigned short*>(&h);
}

// ---- pack weights: W[o, kperm(c,i)], bf16; kperm = (i/32)*288+c*32+(i%32) --
__global__ void prep_w(const float* __restrict__ coef, const float* __restrict__ sb,
                       const float* __restrict__ sp, const float* __restrict__ mask,
                       __hip_bfloat16* __restrict__ W, int O, int I) {
  long idx = (long)blockIdx.x * blockDim.x + threadIdx.x;
  long total = (long)O * (I >> 2);
  if (idx >= total) return;
  int qtr = I >> 2;
  int iq = (int)(idx % qtr);
  int o  = (int)(idx / qtr);
  int i  = iq << 2;
  size_t oi = (size_t)o * I + i;
  float4 mk4 = *(const float4*)(mask + oi);
  float4 sp4 = *(const float4*)(sp + oi);
  float4 sb4 = *(const float4*)(sb + oi);
  float spm[4] = {sp4.x * mk4.x, sp4.y * mk4.y, sp4.z * mk4.z, sp4.w * mk4.w};
  float cf[4][8];
  const float4* cp = (const float4*)(coef + oi * 8);
#pragma unroll
  for (int e = 0; e < 4; e++) {
    float4 a = cp[e * 2], b = cp[e * 2 + 1];
    cf[e][0] = a.x; cf[e][1] = a.y; cf[e][2] = a.z; cf[e][3] = a.w;
    cf[e][4] = b.x; cf[e][5] = b.y; cf[e][6] = b.z; cf[e][7] = b.w;
  }
  __hip_bfloat16* base = W + (size_t)o * (size_t)(9 * I) + (i >> 5) * 288 + (i & 31);
#pragma unroll
  for (int c = 0; c < 8; c++) {
    short4v pk;
#pragma unroll
    for (int e = 0; e < 4; e++) pk[e] = (short)f2bf(cf[e][c] * spm[e]);
    *(short4v*)(base + c * 32) = pk;
  }
  short4v ps;
  ps[0] = (short)f2bf(sb4.x * mk4.x); ps[1] = (short)f2bf(sb4.y * mk4.y);
  ps[2] = (short)f2bf(sb4.z * mk4.z); ps[3] = (short)f2bf(sb4.w * mk4.w);
  *(short4v*)(base + 8 * 32) = ps;
}

// ---- expand activations: Aug[b, kperm(c,i)], 8 elems/thread, 16B stores ---
__device__ __forceinline__ void basis8(float x, float* w, int& j) {
  float u  = (x + 2.2f) * 2.5f;
  float fj = floorf(u);
  j = (int)fj;
  float t  = u - fj;
  float omt = 1.0f - t;
  float t2 = t * t, t3 = t2 * t;
  w[0] = omt * omt * omt * (1.0f / 6.0f);                              // d==3
  w[1] = (3.0f * t3 - 6.0f * t2 + 4.0f) * (1.0f / 6.0f);               // d==2
  w[2] = (-3.0f * t3 + 3.0f * t2 + 3.0f * t + 1.0f) * (1.0f / 6.0f);   // d==1
  w[3] = t3 * (1.0f / 6.0f);                                           // d==0
}

__global__ void expand_aug(const float* __restrict__ src,
                           __hip_bfloat16* __restrict__ aug,
                           long totalOcts, int I) {
  long idx = (long)blockIdx.x * blockDim.x + threadIdx.x;
  if (idx >= totalOcts) return;
  int  oct = I >> 3;
  int  io = (int)(idx % oct);
  long b  = idx / oct;
  int  i  = io << 3;            // octet stays within one 32-block (8|32)
  const float* sp = src + b * (size_t)I + i;
  float4 xa = *(const float4*)sp;
  float4 xb = *(const float4*)(sp + 4);
  float xv[8] = {xa.x, xa.y, xa.z, xa.w, xb.x, xb.y, xb.z, xb.w};

  float w[8][4], s[8];
  int   j[8];
#pragma unroll
  for (int e = 0; e < 8; e++) {
    float xe = xv[e];
    s[e] = xe / (1.0f + __expf(-xe));
    basis8(xe, w[e], j[e]);
  }

  __hip_bfloat16* base = aug + b * (size_t)(9 * I) + (i >> 5) * 288 + (i & 31);
#pragma unroll
  for (int c = 0; c < 8; c++) {
    short8 pk;
#pragma unroll
    for (int e = 0; e < 8; e++) {
      int d = j[e] - c;
      float v = 0.0f;
      v = (d == 0) ? w[e][3] : v;
      v = (d == 1) ? w[e][2] : v;
      v = (d == 2) ? w[e][1] : v;
      v = (d == 3) ? w[e][0] : v;
      pk[e] = (short)f2bf(v);
    }
    *(short8*)(base + c * 32) = pk;
  }
  short8 ps;
#pragma unroll
  for (int e = 0; e < 8; e++) ps[e] = (short)f2bf(s[e]);
  *(short8*)(base + 8 * 32) = ps;
}

// ---- BK=64 GEMM: C[m,n] = sum_k A[m,k]*Bw[n,k] + bias[n], fp32 out --------
// BM=256 x BN (256/128), BK=64, 8 waves = 2M x 4N, 2 LDS buffers.
// LDS rows are 128B; elem (row,kbyte) at row*128 + ((kbyte>>4 ^ (row&7))<<4).
template <int BN>
__global__ __launch_bounds__(512, 2) void gemm64(
    const __hip_bfloat16* __restrict__ A, const __hip_bfloat16* __restrict__ Bw,
    const float* __restrict__ bias, float* __restrict__ Cout, int N, int K) {
  constexpr int WN   = BN / 4;            // per-wave cols
  constexpr int NREP = BN / 64;           // 16-col frags per wave
  constexpr int BGLD = BN / 64;           // B chunks (8KB each) per tile
  constexpr int BUFB = 32768 + BN * 128;  // A + B bytes per buffer
  constexpr int L    = 4 + BGLD;          // GLD16 per tile per thread
  __shared__ __attribute__((aligned(16))) char lds[2 * BUFB];

  const int t = threadIdx.x;
  const int w = t >> 6, l = t & 63;
  const int wr = w >> 2, wc = w & 3;
  const int lr = l & 15;
  const int slot0 = ((l >> 4) ^ (lr & 7)) << 4;   // k-half0 swizzled byte

  // XCD-aware bijective swizzle (grid %8 == 0)
  unsigned nwg = gridDim.x * gridDim.y;
  unsigned lin = blockIdx.y * gridDim.x + blockIdx.x;
  unsigned swz = (lin & 7) * (nwg >> 3) + (lin >> 3);
  unsigned bx = swz % gridDim.x, by = swz / gridDim.x;
  size_t brow = (size_t)by * 256, bcol = (size_t)bx * BN;

  f32x4 acc[8][NREP];
#pragma unroll
  for (int m = 0; m < 8; m++)
#pragma unroll
    for (int n = 0; n < NREP; n++) acc[m][n] = (f32x4){0.f, 0.f, 0.f, 0.f};

  // staging: chunk g = 64 rows x 128B. Thread t -> row g*64+(t>>3), lds slot
  // t&7, which holds source k-slot (t&7)^((t>>3)&7) (pre-swizzled source).
  const int ssl = (((t & 7) ^ ((t >> 3) & 7)) << 3);    // source k elems
  const __hip_bfloat16* gA = A + (brow + (t >> 3)) * (size_t)K + ssl;
  const __hip_bfloat16* gB = Bw + (bcol + (t >> 3)) * (size_t)K + ssl;
  const size_t rs64 = (size_t)64 * K;

  char* ldsp = (char*)lds;

  auto STAGE = [&](int kt, int q) {
    const int k = kt << 6;
    char* bp = ldsp + q * BUFB;
#pragma unroll
    for (int g = 0; g < 4; g++) GLD16(gA + g * rs64 + k, bp + g * 8192 + t * 16);
#pragma unroll
    for (int g = 0; g < BGLD; g++)
      GLD16(gB + g * rs64 + k, bp + 32768 + g * 8192 + t * 16);
  };

  auto COMPUTE = [&](int q) {
    const char* bb = ldsp + q * BUFB;
    const int pa0 = (wr * 128 + lr) * 128 + slot0;          // + m*2048, ^64 k1
    const int pb0 = 32768 + (wc * WN + lr) * 128 + slot0;   // + n*2048, ^64 k1
#pragma unroll
    for (int kh = 0; kh < 2; kh++) {
      const int kx = kh ? 64 : 0;
      short8 bq[NREP], aq[4];
#pragma unroll
      for (int n = 0; n < NREP; n++)
        bq[n] = *(const short8*)(bb + ((pb0 + n * 2048) ^ kx));
#pragma unroll
      for (int m = 0; m < 4; m++)
        aq[m] = *(const short8*)(bb + ((pa0 + m * 2048) ^ kx));
      __builtin_amdgcn_s_setprio(1);
#pragma unroll
      for (int m = 0; m < 4; m++)
#pragma unroll
        for (int n = 0; n < NREP; n++)
          acc[m][n] = __builtin_amdgcn_mfma_f32_16x16x32_bf16(aq[m], bq[n], acc[m][n], 0, 0, 0);
      __builtin_amdgcn_s_setprio(0);
#pragma unroll
      for (int m = 0; m < 4; m++)
        aq[m] = *(const short8*)(bb + ((pa0 + (m + 4) * 2048) ^ kx));
      __builtin_amdgcn_s_setprio(1);
#pragma unroll
      for (int m = 0; m < 4; m++)
#pragma unroll
        for (int n = 0; n < NREP; n++)
          acc[m + 4][n] = __builtin_amdgcn_mfma_f32_16x16x32_bf16(aq[m], bq[n], acc[m + 4][n], 0, 0, 0);
      __builtin_amdgcn_s_setprio(0);
    }
  };

  const int NT = K >> 6;   // 144 (L0) / 288 (L1)

  STAGE(0, 0);
  STAGE(1, 1);
  if constexpr (BN == 256) asm volatile("s_waitcnt vmcnt(8)" ::: "memory");
  else                     asm volatile("s_waitcnt vmcnt(6)" ::: "memory");
  __builtin_amdgcn_s_barrier();

  for (int tt = 0; tt < NT; ++tt) {
    COMPUTE(tt & 1);
    __builtin_amdgcn_s_barrier();           // all reads of buf tt&1 done
    if (tt + 2 < NT) {
      STAGE(tt + 2, tt & 1);                // overwrite just-read buffer
      // outstanding = L(tt+1) + L(tt+2) = 2L -> drain exactly L(tt+1)
      if constexpr (BN == 256) asm volatile("s_waitcnt vmcnt(8)" ::: "memory");
      else                     asm volatile("s_waitcnt vmcnt(6)" ::: "memory");
      __builtin_amdgcn_s_barrier();         // publish
    } else if (tt + 1 < NT) {
      asm volatile("s_waitcnt vmcnt(0)" ::: "memory");   // tail drain
      __builtin_amdgcn_s_barrier();
    }
  }

  // epilogue
  const int orow = (l >> 4) << 2;
#pragma unroll
  for (int n = 0; n < NREP; n++) {
    size_t col = bcol + (size_t)wc * WN + n * 16 + lr;
    float bv = bias[col];
#pragma unroll
    for (int m = 0; m < 8; m++) {
      size_t row = brow + (size_t)wr * 128 + m * 16 + orow;
#pragma unroll
      for (int r = 0; r < 4; r++)
        Cout[(row + r) * (size_t)N + col] = acc[m][n][r] + bv;
    }
  }
}

// ---------------------------------------------------------------------------
extern "C" void kernel_launch(void* const* d_in, const int* in_sizes, int n_in,
                              void* d_out, int out_size, void* d_ws, size_t ws_size,
                              hipStream_t stream) {
  const float* x     = (const float*)d_in[0];
  const float* coef0 = (const float*)d_in[1];
  const float* sb0   = (const float*)d_in[2];
  const float* sp0   = (const float*)d_in[3];
  const float* mask0 = (const float*)d_in[4];
  const float* bias0 = (const float*)d_in[5];
  const float* coef1 = (const float*)d_in[6];
  const float* sb1   = (const float*)d_in[7];
  const float* sp1   = (const float*)d_in[8];
  const float* mask1 = (const float*)d_in[9];
  const float* bias1 = (const float*)d_in[10];
  float* out = (float*)d_out;

  const int B = 8192, D0 = 1024, D1 = 2048, D2 = 1024;
  const int K0 = 9 * D0;   // 9216
  const int K1 = 9 * D1;   // 18432

  char* ws = (char*)d_ws;
  float*          h1  = (float*)ws;                                   // 64 MiB
  __hip_bfloat16* W   = (__hip_bfloat16*)(ws + (size_t)67108864);     // 36 MiB
  __hip_bfloat16* Aug = (__hip_bfloat16*)(ws + (size_t)104857600);

  const bool fullL1 = ws_size >= (size_t)104857600 + (size_t)B * K1 * 2;

  // ---- layer 0: full batch ----
  {
    long nt = (long)D1 * (D0 / 4);
    prep_w<<<(unsigned)((nt + 255) / 256), 256, 0, stream>>>(coef0, sb0, sp0, mask0, W, D1, D0);
    long no = (long)B * (D0 / 8);
    expand_aug<<<(unsigned)((no + 255) / 256), 256, 0, stream>>>(x, Aug, no, D0);
    dim3 g0(D1 / 256, B / 256);  // (8, 32) = 256 blocks
    gemm64<256><<<g0, 512, 0, stream>>>(Aug, W, bias0, h1, D1, K0);
  }

  // ---- layer 1 ----
  {
    long nt = (long)D2 * (D1 / 4);
    prep_w<<<(unsigned)((nt + 255) / 256), 256, 0, stream>>>(coef1, sb1, sp1, mask1, W, D2, D1);
    const int CH = fullL1 ? B : 4096;
    for (int ch = 0; ch < B / CH; ch++) {
      long no = (long)CH * (D1 / 8);
      expand_aug<<<(unsigned)((no + 255) / 256), 256, 0, stream>>>(
          h1 + (size_t)ch * CH * D1, Aug, no, D1);
      dim3 g1(D2 / 128, CH / 256);  // full: (8, 32) = 256 blocks
      gemm64<128><<<g1, 512, 0, stream>>>(Aug, W, bias1,
                                          out + (size_t)ch * CH * D2, D2, K1);
    }
  }
}